// Round 1
// baseline (598.220 us; speedup 1.0000x reference)
//
#include <hip/hip_runtime.h>
#include <math.h>

// DigitCaps dynamic routing. B=512, I=1152, K=8, C=10, D=16, 3 iters.
//
// R5 structure (3.2x win): materialize bf16 u_hat (189 MB) in ws; each routing
// pass streams it once; wave owns a (b,i) row (lane = cd-quad, 40/64 active);
// softmax fully in-register.
// R7 (this round): producer was latency/occupancy-bound (occ 33%: launch_bounds
// (256,4) forced 2 dispatch rounds over a 6-block/CU grid; VALUBusy 34% = W_t
// L2-load latency unhidden at 4 waves/SIMD). -> __launch_bounds__(256,6): all 6
// blocks/CU co-resident (VGPR=64 fits). route_pass was dependency-chain-bound
// (2 chains of shfl+exp+IEEE-div) -> 4-wide unroll + v_rcp_f32 instead of div.

#define UHQ 40          // float4/ushort4 quads per (b,i) row (160 elems)
#define K1_CH 48        // producer i-chunks (24 i each), 4 b per wave
#define K2_CH 12        // route i-chunks per b (96 i each)

__device__ __forceinline__ float dot8(const float4 w0, const float4 w1,
                                      const float4 ua, const float4 ub) {
    return w0.x*ua.x + w0.y*ua.y + w0.z*ua.z + w0.w*ua.w
         + w1.x*ub.x + w1.y*ub.y + w1.z*ub.z + w1.w*ub.w;
}

__device__ __forceinline__ unsigned short bf16_rn(float x) {
    unsigned u = __float_as_uint(x);
    u += 0x7FFFu + ((u >> 16) & 1u);
    return (unsigned short)(u >> 16);
}
__device__ __forceinline__ float bf16_to_f(unsigned short h) {
    return __uint_as_float(((unsigned)h) << 16);
}

// ---------------- W transpose: W[i][c][d][k] -> W_t[i][j][q] (float4 units) ----------------
// Producer lane q needs floats [q*32 .. q*32+32) of row i, as 8 float4 (j=0..7).
// W_t stores quad (i,q,j) at float4 index i*320 + j*40 + q  => lane-consecutive.
__global__ void transpose_W(const float4* __restrict__ W4, float4* __restrict__ Wt4)
{
    int tid = blockIdx.x * 256 + threadIdx.x;
    if (tid >= 1152 * 320) return;
    int i = tid / 320, r = tid - i * 320;
    int q = r >> 3, j = r & 7;
    Wt4[i * 320 + j * 40 + q] = W4[tid];   // read coalesced, scatter within 5 KB row
}

// ---------------- Producer (coalesced W_t): u_hat bf16 + fused pass-0 sum ----------------
// launch_bounds(256,6): grid is 1536 blocks = exactly 6/CU; 6 resident blocks
// run in ONE round (was 4+2 rounds -> 33% occupancy, 34% VALUBusy).
__global__ __launch_bounds__(256, 6)
void produce_uhat_t(const float* __restrict__ u, const float* __restrict__ Wt,
                    unsigned short* __restrict__ uhat_h, float* __restrict__ s0)
{
    const int t = threadIdx.x, lane = t & 63, wv = t >> 6;
    const int gid = blockIdx.x * 4 + wv;
    const int bq  = gid / K1_CH;          // 0..127
    const int ch  = gid - bq * K1_CH;     // 0..47
    const int b0  = bq * 4;
    const int i0  = ch * 24;
    const int q   = lane;
    const bool act = (q < UHQ);

    float4 acc[4];
    #pragma unroll
    for (int bb = 0; bb < 4; ++bb) acc[bb] = make_float4(0.f, 0.f, 0.f, 0.f);

    for (int ii = 0; ii < 24; ++ii) {
        const int i = i0 + ii;
        float4 w4[8];
        if (act) {
            const float4* wb = (const float4*)(Wt + (size_t)i * 1280);
            #pragma unroll
            for (int j = 0; j < 8; ++j) w4[j] = wb[j * 40 + q];   // 640 B contiguous
        }
        #pragma unroll
        for (int bb = 0; bb < 4; ++bb) {
            const int b = b0 + bb;
            const float4* up = (const float4*)(u + ((size_t)b * 1152 + i) * 8);
            const float4 ua = up[0], ub = up[1];   // wave-uniform broadcast
            if (act) {
                float4 uh;
                uh.x = dot8(w4[0], w4[1], ua, ub);
                uh.y = dot8(w4[2], w4[3], ua, ub);
                uh.z = dot8(w4[4], w4[5], ua, ub);
                uh.w = dot8(w4[6], w4[7], ua, ub);
                acc[bb].x += uh.x; acc[bb].y += uh.y;
                acc[bb].z += uh.z; acc[bb].w += uh.w;
                ushort4 h;
                h.x = bf16_rn(uh.x); h.y = bf16_rn(uh.y);
                h.z = bf16_rn(uh.z); h.w = bf16_rn(uh.w);
                ((ushort4*)uhat_h)[((size_t)b * 1152 + i) * UHQ + q] = h;
            }
        }
    }
    if (act) {
#if defined(__HIP_DEVICE_COMPILE__)
        #pragma unroll
        for (int bb = 0; bb < 4; ++bb) {
            float* sp = s0 + (size_t)(b0 + bb) * 160 + q * 4;
            unsafeAtomicAdd(sp + 0, acc[bb].x);
            unsafeAtomicAdd(sp + 1, acc[bb].y);
            unsafeAtomicAdd(sp + 2, acc[bb].z);
            unsafeAtomicAdd(sp + 3, acc[bb].w);
        }
#endif
    }
}

// ---------------- Producer fallback (divergent W, no W_t buffer) ----------------
__global__ __launch_bounds__(256, 6)
void produce_uhat_div(const float* __restrict__ u, const float* __restrict__ W,
                      unsigned short* __restrict__ uhat_h, float* __restrict__ s0)
{
    const int t = threadIdx.x, lane = t & 63, wv = t >> 6;
    const int gid = blockIdx.x * 4 + wv;
    const int bq  = gid / K1_CH;
    const int ch  = gid - bq * K1_CH;
    const int b0  = bq * 4;
    const int i0  = ch * 24;
    const int q   = lane;
    const bool act = (q < UHQ);

    float4 acc[4];
    #pragma unroll
    for (int bb = 0; bb < 4; ++bb) acc[bb] = make_float4(0.f, 0.f, 0.f, 0.f);

    for (int ii = 0; ii < 24; ++ii) {
        const int i = i0 + ii;
        float4 w4[8];
        if (act) {
            const float4* wp = (const float4*)(W + (size_t)i * 1280 + q * 32);
            #pragma unroll
            for (int j = 0; j < 8; ++j) w4[j] = wp[j];
        }
        #pragma unroll
        for (int bb = 0; bb < 4; ++bb) {
            const int b = b0 + bb;
            const float4* up = (const float4*)(u + ((size_t)b * 1152 + i) * 8);
            const float4 ua = up[0], ub = up[1];
            if (act) {
                float4 uh;
                uh.x = dot8(w4[0], w4[1], ua, ub);
                uh.y = dot8(w4[2], w4[3], ua, ub);
                uh.z = dot8(w4[4], w4[5], ua, ub);
                uh.w = dot8(w4[6], w4[7], ua, ub);
                acc[bb].x += uh.x; acc[bb].y += uh.y;
                acc[bb].z += uh.z; acc[bb].w += uh.w;
                ushort4 h;
                h.x = bf16_rn(uh.x); h.y = bf16_rn(uh.y);
                h.z = bf16_rn(uh.z); h.w = bf16_rn(uh.w);
                ((ushort4*)uhat_h)[((size_t)b * 1152 + i) * UHQ + q] = h;
            }
        }
    }
    if (act) {
#if defined(__HIP_DEVICE_COMPILE__)
        #pragma unroll
        for (int bb = 0; bb < 4; ++bb) {
            float* sp = s0 + (size_t)(b0 + bb) * 160 + q * 4;
            unsafeAtomicAdd(sp + 0, acc[bb].x);
            unsafeAtomicAdd(sp + 1, acc[bb].y);
            unsafeAtomicAdd(sp + 2, acc[bb].z);
            unsafeAtomicAdd(sp + 3, acc[bb].w);
        }
#endif
    }
}

// ---------------- Routing pass: stream u_hat once, 4-wide unroll + rcp ----------------
template <int PASS>
__global__ __launch_bounds__(256, 8)
void route_pass(const unsigned short* __restrict__ uhat_h,
                const float* __restrict__ v0g, const float* __restrict__ v1g,
                float* __restrict__ sg)
{
    const int t = threadIdx.x, lane = t & 63, wv = t >> 6;
    const int gid = blockIdx.x * 4 + wv;
    const int b   = gid / K2_CH;          // 0..511
    const int ch  = gid - b * K2_CH;      // 0..11
    const int i0  = ch * 96;
    const int q   = lane;
    const bool act = (q < UHQ);

    float4 va = make_float4(0.f, 0.f, 0.f, 0.f);
    if (act) {
        va = ((const float4*)v0g)[(size_t)b * UHQ + q];
        if (PASS == 2) {
            const float4 vb = ((const float4*)v1g)[(size_t)b * UHQ + q];
            va.x += vb.x; va.y += vb.y; va.z += vb.z; va.w += vb.w;
        }
    }
    float4 sacc = make_float4(0.f, 0.f, 0.f, 0.f);

    const ushort4* up = (const ushort4*)uhat_h;

    for (int ii = 0; ii < 96; ii += 4) {
        const size_t qi = ((size_t)b * 1152 + i0 + ii) * UHQ + q;
        float4 uh[4];
        #pragma unroll
        for (int k = 0; k < 4; ++k)
            uh[k] = make_float4(0.f, 0.f, 0.f, 0.f);
        if (act) {
            #pragma unroll
            for (int k = 0; k < 4; ++k) {
                const ushort4 h = up[qi + (size_t)k * UHQ];
                uh[k].x = bf16_to_f(h.x); uh[k].y = bf16_to_f(h.y);
                uh[k].z = bf16_to_f(h.z); uh[k].w = bf16_to_f(h.w);
            }
        }
        // per-c logit: 4-lane segmented reduction (four independent chains)
        float p[4], e[4], s[4];
        #pragma unroll
        for (int k = 0; k < 4; ++k)
            p[k] = uh[k].x*va.x + uh[k].y*va.y + uh[k].z*va.z + uh[k].w*va.w;
        #pragma unroll
        for (int k = 0; k < 4; ++k) p[k] += __shfl_xor(p[k], 1);
        #pragma unroll
        for (int k = 0; k < 4; ++k) p[k] += __shfl_xor(p[k], 2);
        // softmax, no max-subtraction (|logit| < ~0.5); mask inactive lanes
        #pragma unroll
        for (int k = 0; k < 4; ++k) e[k] = act ? __expf(p[k]) : 0.0f;
        #pragma unroll
        for (int k = 0; k < 4; ++k) s[k] = e[k];
        // xor-butterfly over strides 4..32: every lane gets sum over the 10 c-groups
        #pragma unroll
        for (int k = 0; k < 4; ++k) s[k] += __shfl_xor(s[k], 4);
        #pragma unroll
        for (int k = 0; k < 4; ++k) s[k] += __shfl_xor(s[k], 8);
        #pragma unroll
        for (int k = 0; k < 4; ++k) s[k] += __shfl_xor(s[k], 16);
        #pragma unroll
        for (int k = 0; k < 4; ++k) s[k] += __shfl_xor(s[k], 32);
        // c = e/s via v_rcp_f32 (1-ulp approx; irrelevant vs bf16 u_hat error)
        #pragma unroll
        for (int k = 0; k < 4; ++k) {
            const float c = e[k] * __builtin_amdgcn_rcpf(s[k]);
            sacc.x += c * uh[k].x;
            sacc.y += c * uh[k].y;
            sacc.z += c * uh[k].z;
            sacc.w += c * uh[k].w;
        }
    }
    if (act) {
#if defined(__HIP_DEVICE_COMPILE__)
        float* sp = sg + (size_t)b * 160 + q * 4;
        unsafeAtomicAdd(sp + 0, sacc.x);
        unsafeAtomicAdd(sp + 1, sacc.y);
        unsafeAtomicAdd(sp + 2, sacc.z);
        unsafeAtomicAdd(sp + 3, sacc.w);
#endif
    }
}

// ---------------- squash with pre-scale ----------------
__global__ void squash_scale(const float* __restrict__ s, float* __restrict__ vout,
                             float scale)
{
    int r = blockIdx.x * 256 + threadIdx.x;
    if (r >= 512 * 10) return;
    const float* sp = s + (size_t)r * 16;
    float sv[16];
    float ns = 0.0f;
    #pragma unroll
    for (int d = 0; d < 16; ++d) {
        float x = sp[d] * scale;
        sv[d] = x;
        ns += x * x;
    }
    float sc = ns / ((1.0f + ns) * (sqrtf(ns) + 1e-8f));
    float* o = vout + (size_t)r * 16;
    #pragma unroll
    for (int d = 0; d < 16; ++d) o[d] = sv[d] * sc;
}

// ---------------- tiny-ws fallback (R3-style): thread owns (b,c) ----------------
template <int PASS>
__global__ __launch_bounds__(256, 4)
void pass_fb(const float* __restrict__ u, const float* __restrict__ W,
             const float* __restrict__ v0g, const float* __restrict__ v1g,
             float* __restrict__ s_atomic)
{
    const int t    = threadIdx.x;
    const int lane = t & 63;
    const int wv   = t >> 6;
    const int bsub = lane / 10;
    const int c    = lane - bsub * 10;
    const bool lane_ok = (bsub < 6);
    const int b    = blockIdx.y * 24 + wv * 6 + bsub;
    const bool valid = lane_ok && (b < 512);
    const int bc   = valid ? b : 511;
    const int base = lane_ok ? bsub * 10 : 0;
    const int i0   = blockIdx.x * 24;

    float v[16];
    #pragma unroll
    for (int d = 0; d < 16; ++d) v[d] = 0.0f;
    if (PASS >= 1) {
        const float* vp = v0g + ((size_t)bc * 10 + c) * 16;
        #pragma unroll
        for (int d = 0; d < 16; ++d) v[d] = vp[d];
        if (PASS >= 2) {
            const float* vq = v1g + ((size_t)bc * 10 + c) * 16;
            #pragma unroll
            for (int d = 0; d < 16; ++d) v[d] += vq[d];
        }
    }

    float s_acc[16];
    #pragma unroll
    for (int d = 0; d < 16; ++d) s_acc[d] = 0.0f;

    for (int ii = 0; ii < 24; ++ii) {
        const int i = i0 + ii;
        const float4* up = (const float4*)(u + ((size_t)bc * 1152 + i) * 8);
        const float4 ua = up[0];
        const float4 ub = up[1];
        const float* Wp = W + ((size_t)i * 10 + c) * 128;

        float h[16];
        #pragma unroll
        for (int d = 0; d < 16; ++d) {
            const float4* wp = (const float4*)(Wp + d * 8);
            h[d] = dot8(wp[0], wp[1], ua, ub);
        }

        if (PASS == 0) {
            #pragma unroll
            for (int d = 0; d < 16; ++d) s_acc[d] += h[d];
        } else {
            float lg = 0.0f;
            #pragma unroll
            for (int d = 0; d < 16; ++d) lg += h[d] * v[d];
            float lj[10];
            #pragma unroll
            for (int j = 0; j < 10; ++j) lj[j] = __shfl(lg, base + j);
            float m = lj[0];
            #pragma unroll
            for (int j = 1; j < 10; ++j) m = fmaxf(m, lj[j]);
            float sum = 0.0f;
            #pragma unroll
            for (int j = 0; j < 10; ++j) sum += __expf(lj[j] - m);
            const float coef = __expf(lg - m) / sum;
            #pragma unroll
            for (int d = 0; d < 16; ++d) s_acc[d] += coef * h[d];
        }
    }
    if (PASS == 0) {
        #pragma unroll
        for (int d = 0; d < 16; ++d) s_acc[d] *= 0.1f;
    }
    if (valid) {
#if defined(__HIP_DEVICE_COMPILE__)
        #pragma unroll
        for (int d = 0; d < 16; ++d)
            unsafeAtomicAdd(&s_atomic[((size_t)b * 10 + c) * 16 + d], s_acc[d]);
#endif
    }
}

extern "C" void kernel_launch(void* const* d_in, const int* in_sizes, int n_in,
                              void* d_out, int out_size, void* d_ws, size_t ws_size,
                              hipStream_t stream)
{
    const float* u = (const float*)d_in[0];   // [512,1152,8]
    const float* W = (const float*)d_in[1];   // [1152,10,16,8]
    float* out = (float*)d_out;               // [512,10,16]

    float* v0 = (float*)d_ws;
    float* v1 = v0 + 81920;
    float* s0 = v1 + 81920;
    float* s1 = s0 + 81920;
    float* s2 = s1 + 81920;
    float* wt = s2 + 81920;                   // 1,474,560 f32 (5.9 MB)

    const size_t head   = (size_t)5 * 81920 * sizeof(float);          // 1.64 MB
    const size_t wtsz   = (size_t)1152 * 1280 * sizeof(float);        // 5.90 MB
    const size_t uh_b16 = (size_t)512 * 1152 * 160 * 2;               // 188.7 MB

    hipMemsetAsync(s0, 0, (size_t)3 * 81920 * sizeof(float), stream);

    dim3 blk(256);

    if (ws_size >= head + wtsz + uh_b16) {
        unsigned short* uhh = (unsigned short*)(wt + 1152 * 1280);
        transpose_W<<<1440, blk, 0, stream>>>((const float4*)W, (float4*)wt);
        produce_uhat_t<<<1536, blk, 0, stream>>>(u, wt, uhh, s0);
        squash_scale<<<20, blk, 0, stream>>>(s0, v0, 0.1f);
        route_pass<1><<<1536, blk, 0, stream>>>(uhh, v0, nullptr, s1);
        squash_scale<<<20, blk, 0, stream>>>(s1, v1, 1.0f);
        route_pass<2><<<1536, blk, 0, stream>>>(uhh, v0, v1, s2);
        squash_scale<<<20, blk, 0, stream>>>(s2, out, 1.0f);
    } else if (ws_size >= head + uh_b16) {
        unsigned short* uhh = (unsigned short*)wt;   // no W_t buffer
        produce_uhat_div<<<1536, blk, 0, stream>>>(u, W, uhh, s0);
        squash_scale<<<20, blk, 0, stream>>>(s0, v0, 0.1f);
        route_pass<1><<<1536, blk, 0, stream>>>(uhh, v0, nullptr, s1);
        squash_scale<<<20, blk, 0, stream>>>(s1, v1, 1.0f);
        route_pass<2><<<1536, blk, 0, stream>>>(uhh, v0, v1, s2);
        squash_scale<<<20, blk, 0, stream>>>(s2, out, 1.0f);
    } else {
        dim3 grid(48, 22);
        pass_fb<0><<<grid, blk, 0, stream>>>(u, W, nullptr, nullptr, s0);
        squash_scale<<<20, blk, 0, stream>>>(s0, v0, 1.0f);
        pass_fb<1><<<grid, blk, 0, stream>>>(u, W, v0, nullptr, s1);
        squash_scale<<<20, blk, 0, stream>>>(s1, v1, 1.0f);
        pass_fb<2><<<grid, blk, 0, stream>>>(u, W, v0, v1, s2);
        squash_scale<<<20, blk, 0, stream>>>(s2, out, 1.0f);
    }
}

// Round 2
// 415.376 us; speedup vs baseline: 1.4402x; 1.4402x over previous
//
#include <hip/hip_runtime.h>
#include <math.h>

// DigitCaps dynamic routing. B=512, I=1152, K=8, C=10, D=16, 3 iters.
//
// R5 structure: materialize bf16 u_hat (189 MB) in ws; each routing pass
// streams it once; softmax fully in-register.
// R7 POST-MORTEM: __launch_bounds__(256,6) on the producer capped VGPR at 40
// (< ~56 live) -> scratch spills (FETCH 21->626 MB, WRITE 247->772 MB), 160->433us.
// Occupancy was never the limiter. REVERTED to (256,4)/VGPR=64.
// R8 route restructure: lane = (i_sub 0..3, c 0..15); wave does 4 rows/step.
// Dot over d is lane-local (was 2 shfl/row), exp once per (row,c) (was 4x
// redundant), softmax butterfly xor{1,2,4,8} = 4 shfl per 4 rows (was 4/row).
// DS-pipe ops cut ~6x, VALU ~1.5x; same HBM bytes.

#define UHQ 40          // ushort4 quads per (b,i) row (160 bf16 elems)
#define K1_CH 48        // producer i-chunks (24 i each), 4 b per wave
#define K2_CH 12        // route i-chunks per b (96 i each)

__device__ __forceinline__ float dot8(const float4 w0, const float4 w1,
                                      const float4 ua, const float4 ub) {
    return w0.x*ua.x + w0.y*ua.y + w0.z*ua.z + w0.w*ua.w
         + w1.x*ub.x + w1.y*ub.y + w1.z*ub.z + w1.w*ub.w;
}

__device__ __forceinline__ unsigned short bf16_rn(float x) {
    unsigned u = __float_as_uint(x);
    u += 0x7FFFu + ((u >> 16) & 1u);
    return (unsigned short)(u >> 16);
}
__device__ __forceinline__ float bf16_lo(unsigned p) {   // low bf16 of packed pair
    return __uint_as_float(p << 16);
}
__device__ __forceinline__ float bf16_hi(unsigned p) {   // high bf16 of packed pair
    return __uint_as_float(p & 0xFFFF0000u);
}

// ---------------- W transpose: W[i][c][d][k] -> W_t[i][j][q] (float4 units) ----------------
__global__ void transpose_W(const float4* __restrict__ W4, float4* __restrict__ Wt4)
{
    int tid = blockIdx.x * 256 + threadIdx.x;
    if (tid >= 1152 * 320) return;
    int i = tid / 320, r = tid - i * 320;
    int q = r >> 3, j = r & 7;
    Wt4[i * 320 + j * 40 + q] = W4[tid];   // read coalesced, scatter within 5 KB row
}

// ---------------- Producer (coalesced W_t): u_hat bf16 + fused pass-0 sum ----------------
// (256,4): VGPR=64, no spill. DO NOT raise the min-waves bound: at 6 the
// allocator drops to 40 VGPR and spills w4[8] every iteration (R7: +1.2 GB scratch).
__global__ __launch_bounds__(256, 4)
void produce_uhat_t(const float* __restrict__ u, const float* __restrict__ Wt,
                    unsigned short* __restrict__ uhat_h, float* __restrict__ s0)
{
    const int t = threadIdx.x, lane = t & 63, wv = t >> 6;
    const int gid = blockIdx.x * 4 + wv;
    const int bq  = gid / K1_CH;          // 0..127
    const int ch  = gid - bq * K1_CH;     // 0..47
    const int b0  = bq * 4;
    const int i0  = ch * 24;
    const int q   = lane;
    const bool act = (q < UHQ);

    float4 acc[4];
    #pragma unroll
    for (int bb = 0; bb < 4; ++bb) acc[bb] = make_float4(0.f, 0.f, 0.f, 0.f);

    for (int ii = 0; ii < 24; ++ii) {
        const int i = i0 + ii;
        float4 w4[8];
        if (act) {
            const float4* wb = (const float4*)(Wt + (size_t)i * 1280);
            #pragma unroll
            for (int j = 0; j < 8; ++j) w4[j] = wb[j * 40 + q];   // 640 B contiguous
        }
        #pragma unroll
        for (int bb = 0; bb < 4; ++bb) {
            const int b = b0 + bb;
            const float4* up = (const float4*)(u + ((size_t)b * 1152 + i) * 8);
            const float4 ua = up[0], ub = up[1];   // wave-uniform broadcast
            if (act) {
                float4 uh;
                uh.x = dot8(w4[0], w4[1], ua, ub);
                uh.y = dot8(w4[2], w4[3], ua, ub);
                uh.z = dot8(w4[4], w4[5], ua, ub);
                uh.w = dot8(w4[6], w4[7], ua, ub);
                acc[bb].x += uh.x; acc[bb].y += uh.y;
                acc[bb].z += uh.z; acc[bb].w += uh.w;
                ushort4 h;
                h.x = bf16_rn(uh.x); h.y = bf16_rn(uh.y);
                h.z = bf16_rn(uh.z); h.w = bf16_rn(uh.w);
                ((ushort4*)uhat_h)[((size_t)b * 1152 + i) * UHQ + q] = h;
            }
        }
    }
    if (act) {
#if defined(__HIP_DEVICE_COMPILE__)
        #pragma unroll
        for (int bb = 0; bb < 4; ++bb) {
            float* sp = s0 + (size_t)(b0 + bb) * 160 + q * 4;
            unsafeAtomicAdd(sp + 0, acc[bb].x);
            unsafeAtomicAdd(sp + 1, acc[bb].y);
            unsafeAtomicAdd(sp + 2, acc[bb].z);
            unsafeAtomicAdd(sp + 3, acc[bb].w);
        }
#endif
    }
}

// ---------------- Producer fallback (divergent W, no W_t buffer) ----------------
__global__ __launch_bounds__(256, 4)
void produce_uhat_div(const float* __restrict__ u, const float* __restrict__ W,
                      unsigned short* __restrict__ uhat_h, float* __restrict__ s0)
{
    const int t = threadIdx.x, lane = t & 63, wv = t >> 6;
    const int gid = blockIdx.x * 4 + wv;
    const int bq  = gid / K1_CH;
    const int ch  = gid - bq * K1_CH;
    const int b0  = bq * 4;
    const int i0  = ch * 24;
    const int q   = lane;
    const bool act = (q < UHQ);

    float4 acc[4];
    #pragma unroll
    for (int bb = 0; bb < 4; ++bb) acc[bb] = make_float4(0.f, 0.f, 0.f, 0.f);

    for (int ii = 0; ii < 24; ++ii) {
        const int i = i0 + ii;
        float4 w4[8];
        if (act) {
            const float4* wp = (const float4*)(W + (size_t)i * 1280 + q * 32);
            #pragma unroll
            for (int j = 0; j < 8; ++j) w4[j] = wp[j];
        }
        #pragma unroll
        for (int bb = 0; bb < 4; ++bb) {
            const int b = b0 + bb;
            const float4* up = (const float4*)(u + ((size_t)b * 1152 + i) * 8);
            const float4 ua = up[0], ub = up[1];
            if (act) {
                float4 uh;
                uh.x = dot8(w4[0], w4[1], ua, ub);
                uh.y = dot8(w4[2], w4[3], ua, ub);
                uh.z = dot8(w4[4], w4[5], ua, ub);
                uh.w = dot8(w4[6], w4[7], ua, ub);
                acc[bb].x += uh.x; acc[bb].y += uh.y;
                acc[bb].z += uh.z; acc[bb].w += uh.w;
                ushort4 h;
                h.x = bf16_rn(uh.x); h.y = bf16_rn(uh.y);
                h.z = bf16_rn(uh.z); h.w = bf16_rn(uh.w);
                ((ushort4*)uhat_h)[((size_t)b * 1152 + i) * UHQ + q] = h;
            }
        }
    }
    if (act) {
#if defined(__HIP_DEVICE_COMPILE__)
        #pragma unroll
        for (int bb = 0; bb < 4; ++bb) {
            float* sp = s0 + (size_t)(b0 + bb) * 160 + q * 4;
            unsafeAtomicAdd(sp + 0, acc[bb].x);
            unsafeAtomicAdd(sp + 1, acc[bb].y);
            unsafeAtomicAdd(sp + 2, acc[bb].z);
            unsafeAtomicAdd(sp + 3, acc[bb].w);
        }
#endif
    }
}

// ---------------- Routing pass v2: lane = (i_sub, c); 4 rows per wave-step ----------------
// Each active lane (c<10) owns the full 16-d slice of one (i,c): dot is
// lane-local, exp once per (row,c), softmax denominator = xor{1,2,4,8}
// butterfly inside the 16-lane group (4 shfl per 4 rows). Cross-i_sub
// reduction (xor 16,32) paid once at the end.
template <int PASS>
__global__ __launch_bounds__(256, 4)
void route2(const unsigned short* __restrict__ uhat_h,
            const float* __restrict__ v0g, const float* __restrict__ v1g,
            float* __restrict__ sg)
{
    const int t = threadIdx.x, lane = t & 63, wv = t >> 6;
    const int gid  = blockIdx.x * 4 + wv;
    const int b    = gid / K2_CH;         // 0..511
    const int ch   = gid - b * K2_CH;     // 0..11
    const int i0   = ch * 96;
    const int isub = lane >> 4;           // 0..3
    const int c    = lane & 15;           // 0..15, valid c<10
    const bool act = (c < 10);
    const int cc   = act ? c : 9;         // clamp for v load

    // v[b, cc, 0..15]  (f32)
    float v[16];
    {
        const float4* vp = (const float4*)(v0g + ((size_t)b * 10 + cc) * 16);
        float4 a0 = vp[0], a1 = vp[1], a2 = vp[2], a3 = vp[3];
        if (PASS == 2) {
            const float4* vq = (const float4*)(v1g + ((size_t)b * 10 + cc) * 16);
            float4 b0 = vq[0], b1 = vq[1], b2 = vq[2], b3 = vq[3];
            a0.x += b0.x; a0.y += b0.y; a0.z += b0.z; a0.w += b0.w;
            a1.x += b1.x; a1.y += b1.y; a1.z += b1.z; a1.w += b1.w;
            a2.x += b2.x; a2.y += b2.y; a2.z += b2.z; a2.w += b2.w;
            a3.x += b3.x; a3.y += b3.y; a3.z += b3.z; a3.w += b3.w;
        }
        v[0]=a0.x; v[1]=a0.y; v[2]=a0.z; v[3]=a0.w;
        v[4]=a1.x; v[5]=a1.y; v[6]=a1.z; v[7]=a1.w;
        v[8]=a2.x; v[9]=a2.y; v[10]=a2.z; v[11]=a2.w;
        v[12]=a3.x; v[13]=a3.y; v[14]=a3.z; v[15]=a3.w;
    }

    float sacc[16];
    #pragma unroll
    for (int d = 0; d < 16; ++d) sacc[d] = 0.0f;

    const uint4* up = (const uint4*)uhat_h;   // 8 bf16 per uint4
    // row (b,i) = 160 bf16 = 20 uint4; lane's slice: +c*2 uint4

    #pragma unroll 2
    for (int ii = 0; ii < 96; ii += 4) {
        const int i = i0 + ii + isub;
        const size_t base = ((size_t)b * 1152 + i) * 20 + (size_t)c * 2;
        uint4 h0 = make_uint4(0u, 0u, 0u, 0u);
        uint4 h1 = make_uint4(0u, 0u, 0u, 0u);
        if (act) { h0 = up[base]; h1 = up[base + 1]; }
        float x[16];
        x[0]  = bf16_lo(h0.x); x[1]  = bf16_hi(h0.x);
        x[2]  = bf16_lo(h0.y); x[3]  = bf16_hi(h0.y);
        x[4]  = bf16_lo(h0.z); x[5]  = bf16_hi(h0.z);
        x[6]  = bf16_lo(h0.w); x[7]  = bf16_hi(h0.w);
        x[8]  = bf16_lo(h1.x); x[9]  = bf16_hi(h1.x);
        x[10] = bf16_lo(h1.y); x[11] = bf16_hi(h1.y);
        x[12] = bf16_lo(h1.z); x[13] = bf16_hi(h1.z);
        x[14] = bf16_lo(h1.w); x[15] = bf16_hi(h1.w);
        // lane-local dot, 4 partial chains
        float d0 = x[0]*v[0] + x[4]*v[4] + x[8]*v[8]   + x[12]*v[12];
        float d1 = x[1]*v[1] + x[5]*v[5] + x[9]*v[9]   + x[13]*v[13];
        float d2 = x[2]*v[2] + x[6]*v[6] + x[10]*v[10] + x[14]*v[14];
        float d3 = x[3]*v[3] + x[7]*v[7] + x[11]*v[11] + x[15]*v[15];
        const float logit = (d0 + d1) + (d2 + d3);
        // softmax over c within the 16-lane group (no max-sub: |logit| small)
        const float e = act ? __expf(logit) : 0.0f;
        float ss = e;
        ss += __shfl_xor(ss, 1);
        ss += __shfl_xor(ss, 2);
        ss += __shfl_xor(ss, 4);
        ss += __shfl_xor(ss, 8);
        const float coef = e * __builtin_amdgcn_rcpf(ss);
        #pragma unroll
        for (int d = 0; d < 16; ++d) sacc[d] += coef * x[d];
    }

    // reduce over the 4 i_sub groups: lanes {L, L^16, L^32, L^48}
    #pragma unroll
    for (int d = 0; d < 16; ++d) {
        sacc[d] += __shfl_xor(sacc[d], 16);
        sacc[d] += __shfl_xor(sacc[d], 32);
    }
    if (lane < 10) {
#if defined(__HIP_DEVICE_COMPILE__)
        float* sp = sg + (size_t)b * 160 + c * 16;
        #pragma unroll
        for (int d = 0; d < 16; ++d) unsafeAtomicAdd(sp + d, sacc[d]);
#endif
    }
}

// ---------------- squash with pre-scale ----------------
__global__ void squash_scale(const float* __restrict__ s, float* __restrict__ vout,
                             float scale)
{
    int r = blockIdx.x * 256 + threadIdx.x;
    if (r >= 512 * 10) return;
    const float* sp = s + (size_t)r * 16;
    float sv[16];
    float ns = 0.0f;
    #pragma unroll
    for (int d = 0; d < 16; ++d) {
        float x = sp[d] * scale;
        sv[d] = x;
        ns += x * x;
    }
    float sc = ns / ((1.0f + ns) * (sqrtf(ns) + 1e-8f));
    float* o = vout + (size_t)r * 16;
    #pragma unroll
    for (int d = 0; d < 16; ++d) o[d] = sv[d] * sc;
}

// ---------------- tiny-ws fallback (R3-style): thread owns (b,c) ----------------
template <int PASS>
__global__ __launch_bounds__(256, 4)
void pass_fb(const float* __restrict__ u, const float* __restrict__ W,
             const float* __restrict__ v0g, const float* __restrict__ v1g,
             float* __restrict__ s_atomic)
{
    const int t    = threadIdx.x;
    const int lane = t & 63;
    const int wv   = t >> 6;
    const int bsub = lane / 10;
    const int c    = lane - bsub * 10;
    const bool lane_ok = (bsub < 6);
    const int b    = blockIdx.y * 24 + wv * 6 + bsub;
    const bool valid = lane_ok && (b < 512);
    const int bc   = valid ? b : 511;
    const int base = lane_ok ? bsub * 10 : 0;
    const int i0   = blockIdx.x * 24;

    float v[16];
    #pragma unroll
    for (int d = 0; d < 16; ++d) v[d] = 0.0f;
    if (PASS >= 1) {
        const float* vp = v0g + ((size_t)bc * 10 + c) * 16;
        #pragma unroll
        for (int d = 0; d < 16; ++d) v[d] = vp[d];
        if (PASS >= 2) {
            const float* vq = v1g + ((size_t)bc * 10 + c) * 16;
            #pragma unroll
            for (int d = 0; d < 16; ++d) v[d] += vq[d];
        }
    }

    float s_acc[16];
    #pragma unroll
    for (int d = 0; d < 16; ++d) s_acc[d] = 0.0f;

    for (int ii = 0; ii < 24; ++ii) {
        const int i = i0 + ii;
        const float4* up = (const float4*)(u + ((size_t)bc * 1152 + i) * 8);
        const float4 ua = up[0];
        const float4 ub = up[1];
        const float* Wp = W + ((size_t)i * 10 + c) * 128;

        float h[16];
        #pragma unroll
        for (int d = 0; d < 16; ++d) {
            const float4* wp = (const float4*)(Wp + d * 8);
            h[d] = dot8(wp[0], wp[1], ua, ub);
        }

        if (PASS == 0) {
            #pragma unroll
            for (int d = 0; d < 16; ++d) s_acc[d] += h[d];
        } else {
            float lg = 0.0f;
            #pragma unroll
            for (int d = 0; d < 16; ++d) lg += h[d] * v[d];
            float lj[10];
            #pragma unroll
            for (int j = 0; j < 10; ++j) lj[j] = __shfl(lg, base + j);
            float m = lj[0];
            #pragma unroll
            for (int j = 1; j < 10; ++j) m = fmaxf(m, lj[j]);
            float sum = 0.0f;
            #pragma unroll
            for (int j = 0; j < 10; ++j) sum += __expf(lj[j] - m);
            const float coef = __expf(lg - m) / sum;
            #pragma unroll
            for (int d = 0; d < 16; ++d) s_acc[d] += coef * h[d];
        }
    }
    if (PASS == 0) {
        #pragma unroll
        for (int d = 0; d < 16; ++d) s_acc[d] *= 0.1f;
    }
    if (valid) {
#if defined(__HIP_DEVICE_COMPILE__)
        #pragma unroll
        for (int d = 0; d < 16; ++d)
            unsafeAtomicAdd(&s_atomic[((size_t)b * 10 + c) * 16 + d], s_acc[d]);
#endif
    }
}

extern "C" void kernel_launch(void* const* d_in, const int* in_sizes, int n_in,
                              void* d_out, int out_size, void* d_ws, size_t ws_size,
                              hipStream_t stream)
{
    const float* u = (const float*)d_in[0];   // [512,1152,8]
    const float* W = (const float*)d_in[1];   // [1152,10,16,8]
    float* out = (float*)d_out;               // [512,10,16]

    float* v0 = (float*)d_ws;
    float* v1 = v0 + 81920;
    float* s0 = v1 + 81920;
    float* s1 = s0 + 81920;
    float* s2 = s1 + 81920;
    float* wt = s2 + 81920;                   // 1,474,560 f32 (5.9 MB)

    const size_t head   = (size_t)5 * 81920 * sizeof(float);          // 1.64 MB
    const size_t wtsz   = (size_t)1152 * 1280 * sizeof(float);        // 5.90 MB
    const size_t uh_b16 = (size_t)512 * 1152 * 160 * 2;               // 188.7 MB

    hipMemsetAsync(s0, 0, (size_t)3 * 81920 * sizeof(float), stream);

    dim3 blk(256);

    if (ws_size >= head + wtsz + uh_b16) {
        unsigned short* uhh = (unsigned short*)(wt + 1152 * 1280);
        transpose_W<<<1440, blk, 0, stream>>>((const float4*)W, (float4*)wt);
        produce_uhat_t<<<1536, blk, 0, stream>>>(u, wt, uhh, s0);
        squash_scale<<<20, blk, 0, stream>>>(s0, v0, 0.1f);
        route2<1><<<1536, blk, 0, stream>>>(uhh, v0, nullptr, s1);
        squash_scale<<<20, blk, 0, stream>>>(s1, v1, 1.0f);
        route2<2><<<1536, blk, 0, stream>>>(uhh, v0, v1, s2);
        squash_scale<<<20, blk, 0, stream>>>(s2, out, 1.0f);
    } else if (ws_size >= head + uh_b16) {
        unsigned short* uhh = (unsigned short*)wt;   // no W_t buffer
        produce_uhat_div<<<1536, blk, 0, stream>>>(u, W, uhh, s0);
        squash_scale<<<20, blk, 0, stream>>>(s0, v0, 0.1f);
        route2<1><<<1536, blk, 0, stream>>>(uhh, v0, nullptr, s1);
        squash_scale<<<20, blk, 0, stream>>>(s1, v1, 1.0f);
        route2<2><<<1536, blk, 0, stream>>>(uhh, v0, v1, s2);
        squash_scale<<<20, blk, 0, stream>>>(s2, out, 1.0f);
    } else {
        dim3 grid(48, 22);
        pass_fb<0><<<grid, blk, 0, stream>>>(u, W, nullptr, nullptr, s0);
        squash_scale<<<20, blk, 0, stream>>>(s0, v0, 1.0f);
        pass_fb<1><<<grid, blk, 0, stream>>>(u, W, v0, nullptr, s1);
        squash_scale<<<20, blk, 0, stream>>>(s1, v1, 1.0f);
        pass_fb<2><<<grid, blk, 0, stream>>>(u, W, v0, v1, s2);
        squash_scale<<<20, blk, 0, stream>>>(s2, out, 1.0f);
    }
}

// Round 3
// 336.633 us; speedup vs baseline: 1.7771x; 1.2339x over previous
//
#include <hip/hip_runtime.h>
#include <math.h>

// DigitCaps dynamic routing. B=512, I=1152, K=8, C=10, D=16, 3 iters.
//
// R5 structure: materialize bf16 u_hat (189 MB) in ws; each routing pass
// streams it once; softmax fully in-register.
// R7 POST-MORTEM: launch_bounds(256,6) on producer -> VGPR 40, 1.2 GB scratch
// spill. Never squeeze VGPR below the ~56 live regs. Stay at (256,4).
// R8 POST-MORTEM: route2 per-row ops dropped 2x but I launched 1536 blocks at
// 4 blocks/CU resident = 1.5 dispatch rounds -> 117us (= 75 * 1.5). The same
// geometry throttled the producer all along (occupancy 33%).
// R9: ALL big kernels sized to exactly ONE round: 1024 blocks = 4/CU.
//  - producer: K1_CH 32 (36 i/wave), 4096 waves.
//  - route2:   K2_CH 8 (144 i/wave), 4096 waves + register prefetch (next
//    step's loads issued before current compute -> HBM latency hidden).

#define UHQ 40          // ushort4 quads per (b,i) row (160 bf16 elems)
#define K1_CH 32        // producer i-chunks (36 i each), 4 b per wave
#define K2_CH 8         // route i-chunks per b (144 i each)

__device__ __forceinline__ float dot8(const float4 w0, const float4 w1,
                                      const float4 ua, const float4 ub) {
    return w0.x*ua.x + w0.y*ua.y + w0.z*ua.z + w0.w*ua.w
         + w1.x*ub.x + w1.y*ub.y + w1.z*ub.z + w1.w*ub.w;
}

__device__ __forceinline__ unsigned short bf16_rn(float x) {
    unsigned u = __float_as_uint(x);
    u += 0x7FFFu + ((u >> 16) & 1u);
    return (unsigned short)(u >> 16);
}
__device__ __forceinline__ float bf16_lo(unsigned p) {   // low bf16 of packed pair
    return __uint_as_float(p << 16);
}
__device__ __forceinline__ float bf16_hi(unsigned p) {   // high bf16 of packed pair
    return __uint_as_float(p & 0xFFFF0000u);
}

// ---------------- W transpose: W[i][c][d][k] -> W_t[i][j][q] (float4 units) ----------------
__global__ void transpose_W(const float4* __restrict__ W4, float4* __restrict__ Wt4)
{
    int tid = blockIdx.x * 256 + threadIdx.x;
    if (tid >= 1152 * 320) return;
    int i = tid / 320, r = tid - i * 320;
    int q = r >> 3, j = r & 7;
    Wt4[i * 320 + j * 40 + q] = W4[tid];   // read coalesced, scatter within 5 KB row
}

// ---------------- Producer (coalesced W_t): u_hat bf16 + fused pass-0 sum ----------------
// (256,4): VGPR=64, no spill (R7: bound 6 -> VGPR 40 -> 1.2 GB scratch. Never.)
// Grid 1024 = exactly 4 blocks/CU: one dispatch round.
__global__ __launch_bounds__(256, 4)
void produce_uhat_t(const float* __restrict__ u, const float* __restrict__ Wt,
                    unsigned short* __restrict__ uhat_h, float* __restrict__ s0)
{
    const int t = threadIdx.x, lane = t & 63, wv = t >> 6;
    const int gid = blockIdx.x * 4 + wv;
    const int bq  = gid / K1_CH;          // 0..127
    const int ch  = gid - bq * K1_CH;     // 0..31
    const int b0  = bq * 4;
    const int i0  = ch * 36;
    const int q   = lane;
    const bool act = (q < UHQ);

    float4 acc[4];
    #pragma unroll
    for (int bb = 0; bb < 4; ++bb) acc[bb] = make_float4(0.f, 0.f, 0.f, 0.f);

    for (int ii = 0; ii < 36; ++ii) {
        const int i = i0 + ii;
        float4 w4[8];
        if (act) {
            const float4* wb = (const float4*)(Wt + (size_t)i * 1280);
            #pragma unroll
            for (int j = 0; j < 8; ++j) w4[j] = wb[j * 40 + q];   // 640 B contiguous
        }
        #pragma unroll
        for (int bb = 0; bb < 4; ++bb) {
            const int b = b0 + bb;
            const float4* up = (const float4*)(u + ((size_t)b * 1152 + i) * 8);
            const float4 ua = up[0], ub = up[1];   // wave-uniform broadcast
            if (act) {
                float4 uh;
                uh.x = dot8(w4[0], w4[1], ua, ub);
                uh.y = dot8(w4[2], w4[3], ua, ub);
                uh.z = dot8(w4[4], w4[5], ua, ub);
                uh.w = dot8(w4[6], w4[7], ua, ub);
                acc[bb].x += uh.x; acc[bb].y += uh.y;
                acc[bb].z += uh.z; acc[bb].w += uh.w;
                ushort4 h;
                h.x = bf16_rn(uh.x); h.y = bf16_rn(uh.y);
                h.z = bf16_rn(uh.z); h.w = bf16_rn(uh.w);
                ((ushort4*)uhat_h)[((size_t)b * 1152 + i) * UHQ + q] = h;
            }
        }
    }
    if (act) {
#if defined(__HIP_DEVICE_COMPILE__)
        #pragma unroll
        for (int bb = 0; bb < 4; ++bb) {
            float* sp = s0 + (size_t)(b0 + bb) * 160 + q * 4;
            unsafeAtomicAdd(sp + 0, acc[bb].x);
            unsafeAtomicAdd(sp + 1, acc[bb].y);
            unsafeAtomicAdd(sp + 2, acc[bb].z);
            unsafeAtomicAdd(sp + 3, acc[bb].w);
        }
#endif
    }
}

// ---------------- Producer fallback (divergent W, no W_t buffer) ----------------
__global__ __launch_bounds__(256, 4)
void produce_uhat_div(const float* __restrict__ u, const float* __restrict__ W,
                      unsigned short* __restrict__ uhat_h, float* __restrict__ s0)
{
    const int t = threadIdx.x, lane = t & 63, wv = t >> 6;
    const int gid = blockIdx.x * 4 + wv;
    const int bq  = gid / K1_CH;
    const int ch  = gid - bq * K1_CH;
    const int b0  = bq * 4;
    const int i0  = ch * 36;
    const int q   = lane;
    const bool act = (q < UHQ);

    float4 acc[4];
    #pragma unroll
    for (int bb = 0; bb < 4; ++bb) acc[bb] = make_float4(0.f, 0.f, 0.f, 0.f);

    for (int ii = 0; ii < 36; ++ii) {
        const int i = i0 + ii;
        float4 w4[8];
        if (act) {
            const float4* wp = (const float4*)(W + (size_t)i * 1280 + q * 32);
            #pragma unroll
            for (int j = 0; j < 8; ++j) w4[j] = wp[j];
        }
        #pragma unroll
        for (int bb = 0; bb < 4; ++bb) {
            const int b = b0 + bb;
            const float4* up = (const float4*)(u + ((size_t)b * 1152 + i) * 8);
            const float4 ua = up[0], ub = up[1];
            if (act) {
                float4 uh;
                uh.x = dot8(w4[0], w4[1], ua, ub);
                uh.y = dot8(w4[2], w4[3], ua, ub);
                uh.z = dot8(w4[4], w4[5], ua, ub);
                uh.w = dot8(w4[6], w4[7], ua, ub);
                acc[bb].x += uh.x; acc[bb].y += uh.y;
                acc[bb].z += uh.z; acc[bb].w += uh.w;
                ushort4 h;
                h.x = bf16_rn(uh.x); h.y = bf16_rn(uh.y);
                h.z = bf16_rn(uh.z); h.w = bf16_rn(uh.w);
                ((ushort4*)uhat_h)[((size_t)b * 1152 + i) * UHQ + q] = h;
            }
        }
    }
    if (act) {
#if defined(__HIP_DEVICE_COMPILE__)
        #pragma unroll
        for (int bb = 0; bb < 4; ++bb) {
            float* sp = s0 + (size_t)(b0 + bb) * 160 + q * 4;
            unsafeAtomicAdd(sp + 0, acc[bb].x);
            unsafeAtomicAdd(sp + 1, acc[bb].y);
            unsafeAtomicAdd(sp + 2, acc[bb].z);
            unsafeAtomicAdd(sp + 3, acc[bb].w);
        }
#endif
    }
}

// ---------------- Routing pass v2: lane = (i_sub, c); 4 rows per wave-step ----------------
// Lane (c<10) owns the full 16-d slice of one (i,c): dot lane-local, exp once
// per (row,c), softmax = xor{1,2,4,8} butterfly (4 shfl per 4 rows).
// Register prefetch: next step's 2 uint4 loads issued before current compute.
// Grid 1024 = 4 blocks/CU = one round (R8: 1536 blocks -> 1.5 rounds -> x1.5).
template <int PASS>
__global__ __launch_bounds__(256, 4)
void route2(const unsigned short* __restrict__ uhat_h,
            const float* __restrict__ v0g, const float* __restrict__ v1g,
            float* __restrict__ sg)
{
    const int t = threadIdx.x, lane = t & 63, wv = t >> 6;
    const int gid  = blockIdx.x * 4 + wv;
    const int b    = gid / K2_CH;         // 0..511
    const int ch   = gid - b * K2_CH;     // 0..7
    const int i0   = ch * 144;
    const int isub = lane >> 4;           // 0..3
    const int c    = lane & 15;           // 0..15, valid c<10
    const bool act = (c < 10);
    const int cc   = act ? c : 9;         // clamp for v load

    // v[b, cc, 0..15]  (f32)
    float v[16];
    {
        const float4* vp = (const float4*)(v0g + ((size_t)b * 10 + cc) * 16);
        float4 a0 = vp[0], a1 = vp[1], a2 = vp[2], a3 = vp[3];
        if (PASS == 2) {
            const float4* vq = (const float4*)(v1g + ((size_t)b * 10 + cc) * 16);
            float4 b0 = vq[0], b1 = vq[1], b2 = vq[2], b3 = vq[3];
            a0.x += b0.x; a0.y += b0.y; a0.z += b0.z; a0.w += b0.w;
            a1.x += b1.x; a1.y += b1.y; a1.z += b1.z; a1.w += b1.w;
            a2.x += b2.x; a2.y += b2.y; a2.z += b2.z; a2.w += b2.w;
            a3.x += b3.x; a3.y += b3.y; a3.z += b3.z; a3.w += b3.w;
        }
        v[0]=a0.x; v[1]=a0.y; v[2]=a0.z; v[3]=a0.w;
        v[4]=a1.x; v[5]=a1.y; v[6]=a1.z; v[7]=a1.w;
        v[8]=a2.x; v[9]=a2.y; v[10]=a2.z; v[11]=a2.w;
        v[12]=a3.x; v[13]=a3.y; v[14]=a3.z; v[15]=a3.w;
    }

    float sacc[16];
    #pragma unroll
    for (int d = 0; d < 16; ++d) sacc[d] = 0.0f;

    const uint4* up = (const uint4*)uhat_h;   // 8 bf16 per uint4
    // row (b,i) = 160 bf16 = 20 uint4; lane's slice: +c*2 uint4
    // step stride (4 rows) = 80 uint4

    size_t base = ((size_t)b * 1152 + i0 + isub) * 20 + (size_t)c * 2;
    uint4 h0 = make_uint4(0u,0u,0u,0u), h1 = make_uint4(0u,0u,0u,0u);
    if (act) { h0 = up[base]; h1 = up[base + 1]; }

    for (int ii = 0; ii < 144; ii += 4) {
        // prefetch next step before touching current data
        uint4 n0 = make_uint4(0u,0u,0u,0u), n1 = make_uint4(0u,0u,0u,0u);
        if (act && (ii + 4 < 144)) { n0 = up[base + 80]; n1 = up[base + 81]; }

        float x[16];
        x[0]  = bf16_lo(h0.x); x[1]  = bf16_hi(h0.x);
        x[2]  = bf16_lo(h0.y); x[3]  = bf16_hi(h0.y);
        x[4]  = bf16_lo(h0.z); x[5]  = bf16_hi(h0.z);
        x[6]  = bf16_lo(h0.w); x[7]  = bf16_hi(h0.w);
        x[8]  = bf16_lo(h1.x); x[9]  = bf16_hi(h1.x);
        x[10] = bf16_lo(h1.y); x[11] = bf16_hi(h1.y);
        x[12] = bf16_lo(h1.z); x[13] = bf16_hi(h1.z);
        x[14] = bf16_lo(h1.w); x[15] = bf16_hi(h1.w);
        // lane-local dot, 4 partial chains
        float d0 = x[0]*v[0] + x[4]*v[4] + x[8]*v[8]   + x[12]*v[12];
        float d1 = x[1]*v[1] + x[5]*v[5] + x[9]*v[9]   + x[13]*v[13];
        float d2 = x[2]*v[2] + x[6]*v[6] + x[10]*v[10] + x[14]*v[14];
        float d3 = x[3]*v[3] + x[7]*v[7] + x[11]*v[11] + x[15]*v[15];
        const float logit = (d0 + d1) + (d2 + d3);
        // softmax over c within the 16-lane group (no max-sub: |logit| small)
        const float e = act ? __expf(logit) : 0.0f;
        float ss = e;
        ss += __shfl_xor(ss, 1);
        ss += __shfl_xor(ss, 2);
        ss += __shfl_xor(ss, 4);
        ss += __shfl_xor(ss, 8);
        const float coef = e * __builtin_amdgcn_rcpf(ss);
        #pragma unroll
        for (int d = 0; d < 16; ++d) sacc[d] += coef * x[d];

        h0 = n0; h1 = n1; base += 80;
    }

    // reduce over the 4 i_sub groups: lanes {L, L^16, L^32, L^48}
    #pragma unroll
    for (int d = 0; d < 16; ++d) {
        sacc[d] += __shfl_xor(sacc[d], 16);
        sacc[d] += __shfl_xor(sacc[d], 32);
    }
    if (lane < 10) {
#if defined(__HIP_DEVICE_COMPILE__)
        float* sp = sg + (size_t)b * 160 + c * 16;
        #pragma unroll
        for (int d = 0; d < 16; ++d) unsafeAtomicAdd(sp + d, sacc[d]);
#endif
    }
}

// ---------------- squash with pre-scale ----------------
__global__ void squash_scale(const float* __restrict__ s, float* __restrict__ vout,
                             float scale)
{
    int r = blockIdx.x * 256 + threadIdx.x;
    if (r >= 512 * 10) return;
    const float* sp = s + (size_t)r * 16;
    float sv[16];
    float ns = 0.0f;
    #pragma unroll
    for (int d = 0; d < 16; ++d) {
        float x = sp[d] * scale;
        sv[d] = x;
        ns += x * x;
    }
    float sc = ns / ((1.0f + ns) * (sqrtf(ns) + 1e-8f));
    float* o = vout + (size_t)r * 16;
    #pragma unroll
    for (int d = 0; d < 16; ++d) o[d] = sv[d] * sc;
}

// ---------------- tiny-ws fallback (R3-style): thread owns (b,c) ----------------
template <int PASS>
__global__ __launch_bounds__(256, 4)
void pass_fb(const float* __restrict__ u, const float* __restrict__ W,
             const float* __restrict__ v0g, const float* __restrict__ v1g,
             float* __restrict__ s_atomic)
{
    const int t    = threadIdx.x;
    const int lane = t & 63;
    const int wv   = t >> 6;
    const int bsub = lane / 10;
    const int c    = lane - bsub * 10;
    const bool lane_ok = (bsub < 6);
    const int b    = blockIdx.y * 24 + wv * 6 + bsub;
    const bool valid = lane_ok && (b < 512);
    const int bc   = valid ? b : 511;
    const int base = lane_ok ? bsub * 10 : 0;
    const int i0   = blockIdx.x * 24;

    float v[16];
    #pragma unroll
    for (int d = 0; d < 16; ++d) v[d] = 0.0f;
    if (PASS >= 1) {
        const float* vp = v0g + ((size_t)bc * 10 + c) * 16;
        #pragma unroll
        for (int d = 0; d < 16; ++d) v[d] = vp[d];
        if (PASS >= 2) {
            const float* vq = v1g + ((size_t)bc * 10 + c) * 16;
            #pragma unroll
            for (int d = 0; d < 16; ++d) v[d] += vq[d];
        }
    }

    float s_acc[16];
    #pragma unroll
    for (int d = 0; d < 16; ++d) s_acc[d] = 0.0f;

    for (int ii = 0; ii < 24; ++ii) {
        const int i = i0 + ii;
        const float4* up = (const float4*)(u + ((size_t)bc * 1152 + i) * 8);
        const float4 ua = up[0];
        const float4 ub = up[1];
        const float* Wp = W + ((size_t)i * 10 + c) * 128;

        float h[16];
        #pragma unroll
        for (int d = 0; d < 16; ++d) {
            const float4* wp = (const float4*)(Wp + d * 8);
            h[d] = dot8(wp[0], wp[1], ua, ub);
        }

        if (PASS == 0) {
            #pragma unroll
            for (int d = 0; d < 16; ++d) s_acc[d] += h[d];
        } else {
            float lg = 0.0f;
            #pragma unroll
            for (int d = 0; d < 16; ++d) lg += h[d] * v[d];
            float lj[10];
            #pragma unroll
            for (int j = 0; j < 10; ++j) lj[j] = __shfl(lg, base + j);
            float m = lj[0];
            #pragma unroll
            for (int j = 1; j < 10; ++j) m = fmaxf(m, lj[j]);
            float sum = 0.0f;
            #pragma unroll
            for (int j = 0; j < 10; ++j) sum += __expf(lj[j] - m);
            const float coef = __expf(lg - m) / sum;
            #pragma unroll
            for (int d = 0; d < 16; ++d) s_acc[d] += coef * h[d];
        }
    }
    if (PASS == 0) {
        #pragma unroll
        for (int d = 0; d < 16; ++d) s_acc[d] *= 0.1f;
    }
    if (valid) {
#if defined(__HIP_DEVICE_COMPILE__)
        #pragma unroll
        for (int d = 0; d < 16; ++d)
            unsafeAtomicAdd(&s_atomic[((size_t)b * 10 + c) * 16 + d], s_acc[d]);
#endif
    }
}

extern "C" void kernel_launch(void* const* d_in, const int* in_sizes, int n_in,
                              void* d_out, int out_size, void* d_ws, size_t ws_size,
                              hipStream_t stream)
{
    const float* u = (const float*)d_in[0];   // [512,1152,8]
    const float* W = (const float*)d_in[1];   // [1152,10,16,8]
    float* out = (float*)d_out;               // [512,10,16]

    float* v0 = (float*)d_ws;
    float* v1 = v0 + 81920;
    float* s0 = v1 + 81920;
    float* s1 = s0 + 81920;
    float* s2 = s1 + 81920;
    float* wt = s2 + 81920;                   // 1,474,560 f32 (5.9 MB)

    const size_t head   = (size_t)5 * 81920 * sizeof(float);          // 1.64 MB
    const size_t wtsz   = (size_t)1152 * 1280 * sizeof(float);        // 5.90 MB
    const size_t uh_b16 = (size_t)512 * 1152 * 160 * 2;               // 188.7 MB

    hipMemsetAsync(s0, 0, (size_t)3 * 81920 * sizeof(float), stream);

    dim3 blk(256);

    if (ws_size >= head + wtsz + uh_b16) {
        unsigned short* uhh = (unsigned short*)(wt + 1152 * 1280);
        transpose_W<<<1440, blk, 0, stream>>>((const float4*)W, (float4*)wt);
        produce_uhat_t<<<1024, blk, 0, stream>>>(u, wt, uhh, s0);
        squash_scale<<<20, blk, 0, stream>>>(s0, v0, 0.1f);
        route2<1><<<1024, blk, 0, stream>>>(uhh, v0, nullptr, s1);
        squash_scale<<<20, blk, 0, stream>>>(s1, v1, 1.0f);
        route2<2><<<1024, blk, 0, stream>>>(uhh, v0, v1, s2);
        squash_scale<<<20, blk, 0, stream>>>(s2, out, 1.0f);
    } else if (ws_size >= head + uh_b16) {
        unsigned short* uhh = (unsigned short*)wt;   // no W_t buffer
        produce_uhat_div<<<1024, blk, 0, stream>>>(u, W, uhh, s0);
        squash_scale<<<20, blk, 0, stream>>>(s0, v0, 0.1f);
        route2<1><<<1024, blk, 0, stream>>>(uhh, v0, nullptr, s1);
        squash_scale<<<20, blk, 0, stream>>>(s1, v1, 1.0f);
        route2<2><<<1024, blk, 0, stream>>>(uhh, v0, v1, s2);
        squash_scale<<<20, blk, 0, stream>>>(s2, out, 1.0f);
    } else {
        dim3 grid(48, 22);
        pass_fb<0><<<grid, blk, 0, stream>>>(u, W, nullptr, nullptr, s0);
        squash_scale<<<20, blk, 0, stream>>>(s0, v0, 1.0f);
        pass_fb<1><<<grid, blk, 0, stream>>>(u, W, v0, nullptr, s1);
        squash_scale<<<20, blk, 0, stream>>>(s1, v1, 1.0f);
        pass_fb<2><<<grid, blk, 0, stream>>>(u, W, v0, v1, s2);
        squash_scale<<<20, blk, 0, stream>>>(s2, out, 1.0f);
    }
}